// Round 1
// baseline (6013.519 us; speedup 1.0000x reference)
//
#include <hip/hip_runtime.h>
#include <math.h>

#define B 2
#define T 2048
#define D 2048
#define H 16
#define KV 4
#define HD 128
#define REP (H / KV)

// ---------------------------------------------------------------------------
// Generic fp32 GEMM: C[M,N] = A[M,K] @ Bm[K,N], all row-major.
// 64x64 tile, BK=16, 256 threads, 4x4 micro-tile per thread.
// ---------------------------------------------------------------------------
template<int BM, int BN, int BK>
__global__ __launch_bounds__(256) void gemm_f32(
    const float* __restrict__ A, const float* __restrict__ Bm,
    float* __restrict__ C, int M, int N, int K)
{
    __shared__ float As[BK][BM + 4];   // +4 pad keeps float4 alignment, breaks pow2 stride
    __shared__ float Bs[BK][BN + 4];

    const int tid = threadIdx.x;
    const int tx = tid & 15;          // 0..15 -> N direction (4 cols each)
    const int ty = tid >> 4;          // 0..15 -> M direction (4 rows each)
    const int m0 = blockIdx.y * BM;
    const int n0 = blockIdx.x * BN;

    float acc[4][4] = {};

    for (int k0 = 0; k0 < K; k0 += BK) {
        // Load A tile (BM x BK), store transposed As[k][m]
        #pragma unroll
        for (int i = 0; i < (BM * BK) / 256; ++i) {
            int e = tid + 256 * i;
            int r = e / BK, c = e % BK;
            As[c][r] = A[(size_t)(m0 + r) * K + (k0 + c)];
        }
        // Load B tile (BK x BN), Bs[k][n]
        #pragma unroll
        for (int i = 0; i < (BK * BN) / 256; ++i) {
            int e = tid + 256 * i;
            int r = e / BN, c = e % BN;
            Bs[r][c] = Bm[(size_t)(k0 + r) * N + (n0 + c)];
        }
        __syncthreads();

        #pragma unroll
        for (int k = 0; k < BK; ++k) {
            float4 a4 = *reinterpret_cast<const float4*>(&As[k][ty * 4]);
            float4 b4 = *reinterpret_cast<const float4*>(&Bs[k][tx * 4]);
            float a[4] = {a4.x, a4.y, a4.z, a4.w};
            float b[4] = {b4.x, b4.y, b4.z, b4.w};
            #pragma unroll
            for (int i = 0; i < 4; ++i)
                #pragma unroll
                for (int j = 0; j < 4; ++j)
                    acc[i][j] += a[i] * b[j];
        }
        __syncthreads();
    }

    #pragma unroll
    for (int i = 0; i < 4; ++i) {
        float4 o4 = make_float4(acc[i][0], acc[i][1], acc[i][2], acc[i][3]);
        *reinterpret_cast<float4*>(&C[(size_t)(m0 + ty * 4 + i) * N + n0 + tx * 4]) = o4;
    }
}

// ---------------------------------------------------------------------------
// RMSNorm + RoPE on q and k. One 64-lane wave per head-row (HD=128 = 64 pairs).
// Lane i owns the pair (2i, 2i+1). q rows first, then k rows.
// ---------------------------------------------------------------------------
__global__ __launch_bounds__(256) void norm_rope(
    float* __restrict__ q, float* __restrict__ k,
    const float* __restrict__ qw, const float* __restrict__ kw,
    const float* __restrict__ fcos, const float* __restrict__ fsin)
{
    const int wid  = (blockIdx.x * blockDim.x + threadIdx.x) >> 6;
    const int lane = threadIdx.x & 63;
    const int QROWS = B * T * H;

    float* base;
    const float* w;
    int t;
    if (wid < QROWS) {
        t = (wid / H) % T;                    // wid = (b*T + t)*H + h
        base = q + (size_t)wid * HD;
        w = qw;
    } else {
        int rr = wid - QROWS;                 // rr = (b*T + t)*KV + g
        t = (rr / KV) % T;
        base = k + (size_t)rr * HD;
        w = kw;
    }

    float e = base[2 * lane];
    float o = base[2 * lane + 1];

    float ss = e * e + o * o;
    #pragma unroll
    for (int off = 32; off; off >>= 1) ss += __shfl_xor(ss, off);

    const float rinv = rsqrtf(ss * (1.0f / HD) + 1e-6f);
    e *= rinv * w[2 * lane];
    o *= rinv * w[2 * lane + 1];

    const float c = fcos[t * (HD / 2) + lane];
    const float s = fsin[t * (HD / 2) + lane];
    base[2 * lane]     = e * c - o * s;
    base[2 * lane + 1] = e * s + o * c;
}

// ---------------------------------------------------------------------------
// Causal GQA flash attention, one wave per (b, h, t) query row.
// Lane holds q[lane], q[lane+64]; online softmax; O written over the q row
// (safe: each wave reads only its own q row into registers first).
// ---------------------------------------------------------------------------
__global__ __launch_bounds__(256) void attn(
    const float* __restrict__ q, const float* __restrict__ k,
    const float* __restrict__ v, float* __restrict__ o)
{
    const int wid  = (blockIdx.x * blockDim.x + threadIdx.x) >> 6;
    const int lane = threadIdx.x & 63;

    const int t  = wid % T;          // consecutive waves share (b,h) -> K/V L2 reuse
    const int bh = wid / T;
    const int h  = bh % H;
    const int b  = bh / H;
    const int g  = h / REP;

    const float* qrow = q + ((size_t)(b * T + t) * H + h) * HD;
    const float q0 = qrow[lane];
    const float q1 = qrow[lane + 64];
    const float scale = 0.08838834764831845f;   // 1/sqrt(128)

    float m = -1e30f, l = 0.f, o0 = 0.f, o1 = 0.f;

    for (int j = 0; j <= t; ++j) {
        const float* kr = k + ((size_t)(b * T + j) * KV + g) * HD;
        const float* vr = v + ((size_t)(b * T + j) * KV + g) * HD;
        const float k0 = kr[lane];
        const float k1 = kr[lane + 64];
        const float v0 = vr[lane];
        const float v1 = vr[lane + 64];

        float s = q0 * k0 + q1 * k1;
        #pragma unroll
        for (int off = 32; off; off >>= 1) s += __shfl_xor(s, off);
        s *= scale;

        const float nm    = fmaxf(m, s);
        const float alpha = __expf(m - nm);
        const float p     = __expf(s - nm);
        l  = l * alpha + p;
        o0 = o0 * alpha + p * v0;
        o1 = o1 * alpha + p * v1;
        m  = nm;
    }

    float* orow = o + ((size_t)(b * T + t) * H + h) * HD;
    const float inv = 1.0f / l;
    orow[lane]      = o0 * inv;
    orow[lane + 64] = o1 * inv;
}

// ---------------------------------------------------------------------------
extern "C" void kernel_launch(void* const* d_in, const int* in_sizes, int n_in,
                              void* d_out, int out_size, void* d_ws, size_t ws_size,
                              hipStream_t stream) {
    const float* x  = (const float*)d_in[0];
    const float* wq = (const float*)d_in[1];
    const float* wk = (const float*)d_in[2];
    const float* wv = (const float*)d_in[3];
    const float* wo = (const float*)d_in[4];
    const float* qw = (const float*)d_in[5];
    const float* kw = (const float*)d_in[6];
    const float* fc = (const float*)d_in[7];
    const float* fs = (const float*)d_in[8];
    float* out = (float*)d_out;

    float* qbuf = (float*)d_ws;                          // B*T*H*HD  (also attn out)
    float* kbuf = qbuf + (size_t)B * T * H * HD;         // B*T*KV*HD
    float* vbuf = kbuf + (size_t)B * T * KV * HD;        // B*T*KV*HD

    const int M = B * T;           // 4096
    dim3 blk(256);

    // QKV projections
    gemm_f32<64, 64, 16><<<dim3((H * HD) / 64, M / 64), blk, 0, stream>>>(
        x, wq, qbuf, M, H * HD, D);
    gemm_f32<64, 64, 16><<<dim3((KV * HD) / 64, M / 64), blk, 0, stream>>>(
        x, wk, kbuf, M, KV * HD, D);
    gemm_f32<64, 64, 16><<<dim3((KV * HD) / 64, M / 64), blk, 0, stream>>>(
        x, wv, vbuf, M, KV * HD, D);

    // RMSNorm + RoPE on q and k (one wave per row)
    {
        int waves = B * T * (H + KV);
        norm_rope<<<dim3((waves * 64) / 256), blk, 0, stream>>>(qbuf, kbuf, qw, kw, fc, fs);
    }

    // Causal GQA attention, O overwrites qbuf
    {
        int waves = B * H * T;
        attn<<<dim3((waves * 64) / 256), blk, 0, stream>>>(qbuf, kbuf, vbuf, qbuf);
    }

    // Output projection
    gemm_f32<64, 64, 16><<<dim3(D / 64, M / 64), blk, 0, stream>>>(
        qbuf, wo, out, M, D, D);
}

// Round 2
// 1658.959 us; speedup vs baseline: 3.6249x; 3.6249x over previous
//
#include <hip/hip_runtime.h>
#include <math.h>

#define B 2
#define T 2048
#define D 2048
#define H 16
#define KV 4
#define HD 128
#define REP (H / KV)

typedef __attribute__((ext_vector_type(8))) short bf16x8;
typedef __attribute__((ext_vector_type(4))) float f32x4;

// fp32 -> bf16 (RNE), bit-level (no header dependency)
__device__ __forceinline__ short f2bf(float f) {
    unsigned int u = __float_as_uint(f);
    unsigned int r = (u + 0x7fffu + ((u >> 16) & 1u)) >> 16;
    return (short)r;
}

__device__ __forceinline__ bf16x8 pack8(float4 a, float4 b, float s) {
    bf16x8 r;
    r[0] = f2bf(a.x * s); r[1] = f2bf(a.y * s); r[2] = f2bf(a.z * s); r[3] = f2bf(a.w * s);
    r[4] = f2bf(b.x * s); r[5] = f2bf(b.y * s); r[6] = f2bf(b.z * s); r[7] = f2bf(b.w * s);
    return r;
}

// ---------------------------------------------------------------------------
// fp32 GEMM: C[M,N] = A[M,K] @ Bm[K,N], row-major. MODE 0: fp32 C.
// MODE 1: write C transposed as bf16: vt[(b*N + n)*T + t]  (m = b*T + t).
// ---------------------------------------------------------------------------
template<int BM, int BN, int BK, int MODE>
__global__ __launch_bounds__(256) void gemm_f32(
    const float* __restrict__ A, const float* __restrict__ Bm,
    void* __restrict__ Cv, int M, int N, int K)
{
    __shared__ float As[BK][BM + 4];
    __shared__ float Bs[BK][BN + 4];

    const int tid = threadIdx.x;
    const int tx = tid & 15;
    const int ty = tid >> 4;
    const int m0 = blockIdx.y * BM;
    const int n0 = blockIdx.x * BN;

    float acc[4][4] = {};

    for (int k0 = 0; k0 < K; k0 += BK) {
        #pragma unroll
        for (int i = 0; i < (BM * BK) / 256; ++i) {
            int e = tid + 256 * i;
            int r = e / BK, c = e % BK;
            As[c][r] = A[(size_t)(m0 + r) * K + (k0 + c)];
        }
        #pragma unroll
        for (int i = 0; i < (BK * BN) / 256; ++i) {
            int e = tid + 256 * i;
            int r = e / BN, c = e % BN;
            Bs[r][c] = Bm[(size_t)(k0 + r) * N + (n0 + c)];
        }
        __syncthreads();

        #pragma unroll
        for (int k = 0; k < BK; ++k) {
            float4 a4 = *reinterpret_cast<const float4*>(&As[k][ty * 4]);
            float4 b4 = *reinterpret_cast<const float4*>(&Bs[k][tx * 4]);
            float a[4] = {a4.x, a4.y, a4.z, a4.w};
            float b[4] = {b4.x, b4.y, b4.z, b4.w};
            #pragma unroll
            for (int i = 0; i < 4; ++i)
                #pragma unroll
                for (int j = 0; j < 4; ++j)
                    acc[i][j] += a[i] * b[j];
        }
        __syncthreads();
    }

    if (MODE == 0) {
        float* C = (float*)Cv;
        #pragma unroll
        for (int i = 0; i < 4; ++i) {
            float4 o4 = make_float4(acc[i][0], acc[i][1], acc[i][2], acc[i][3]);
            *reinterpret_cast<float4*>(&C[(size_t)(m0 + ty * 4 + i) * N + n0 + tx * 4]) = o4;
        }
    } else {
        // transposed bf16 write for V: vt[(b*N + n) * T + t], m = b*T + t
        short* Ct = (short*)Cv;
        #pragma unroll
        for (int i = 0; i < 4; ++i) {
            int m = m0 + ty * 4 + i;
            int bb = m >> 11;          // m / T
            int t  = m & (T - 1);
            #pragma unroll
            for (int j = 0; j < 4; ++j) {
                int n = n0 + tx * 4 + j;
                Ct[((size_t)bb * N + n) * T + t] = f2bf(acc[i][j]);
            }
        }
    }
}

// ---------------------------------------------------------------------------
// RMSNorm + RoPE on q and k (fp32, in place). One wave per head-row.
// ---------------------------------------------------------------------------
__global__ __launch_bounds__(256) void norm_rope(
    float* __restrict__ q, float* __restrict__ k,
    const float* __restrict__ qw, const float* __restrict__ kw,
    const float* __restrict__ fcos, const float* __restrict__ fsin)
{
    const int wid  = (blockIdx.x * blockDim.x + threadIdx.x) >> 6;
    const int lane = threadIdx.x & 63;
    const int QROWS = B * T * H;

    float* base;
    const float* w;
    int t;
    if (wid < QROWS) {
        t = (wid / H) % T;
        base = q + (size_t)wid * HD;
        w = qw;
    } else {
        int rr = wid - QROWS;
        t = (rr / KV) % T;
        base = k + (size_t)rr * HD;
        w = kw;
    }

    float e = base[2 * lane];
    float o = base[2 * lane + 1];

    float ss = e * e + o * o;
    #pragma unroll
    for (int off = 32; off; off >>= 1) ss += __shfl_xor(ss, off);

    const float rinv = rsqrtf(ss * (1.0f / HD) + 1e-6f);
    e *= rinv * w[2 * lane];
    o *= rinv * w[2 * lane + 1];

    const float c = fcos[t * (HD / 2) + lane];
    const float s = fsin[t * (HD / 2) + lane];
    base[2 * lane]     = e * c - o * s;
    base[2 * lane + 1] = e * s + o * c;
}

// ---------------------------------------------------------------------------
// MFMA flash attention (bf16 inputs, fp32 accum).
// Grid: B*H*(T/64) workgroups of 256 threads (4 waves).
// Wave w owns q rows [qb*64 + w*16, +16). K staged [64][136] bf16;
// V staged transposed [128][72] bf16 (from pre-transposed global vt).
// P round-trips through per-wave fp32 LDS tile (C-layout -> A-layout).
// O (fp32) overwrites the q rows in qob.
// ---------------------------------------------------------------------------
#define KS_STRIDE 136
#define VT_STRIDE 72
#define PF_STRIDE 68
// 1/sqrt(128) * log2(e): scores land in log2 domain -> exp2f softmax
#define QSCALE 0.1275177f

__global__ __launch_bounds__(256) void attn_mfma(
    float* qob, const float* __restrict__ kb_, const short* __restrict__ vtb)
{
    __shared__ short Ks[64 * KS_STRIDE];
    __shared__ short Vt[128 * VT_STRIDE];
    __shared__ float Pf[4 * 16 * PF_STRIDE];

    const int tid  = threadIdx.x;
    const int w    = tid >> 6;
    const int lane = tid & 63;
    const int quad = lane >> 4;
    const int n16  = lane & 15;

    const int bhq = blockIdx.x;
    const int qb  = 31 - (bhq & 31);      // descending qb: heavy blocks first
    const int h   = (bhq >> 5) & 15;
    const int b   = bhq >> 9;
    const int g   = h >> 2;               // h / REP

    // ---- load Q fragments (A-layout: m = lane&15, k = quad*8 + j) ----
    bf16x8 qf[4];
    {
        const int qrow = qb * 64 + w * 16 + n16;
        const float* qp = qob + ((size_t)(b * T + qrow) * H + h) * HD;
        #pragma unroll
        for (int c = 0; c < 4; ++c) {
            float4 x0 = *reinterpret_cast<const float4*>(qp + c * 32 + quad * 8);
            float4 x1 = *reinterpret_cast<const float4*>(qp + c * 32 + quad * 8 + 4);
            qf[c] = pack8(x0, x1, QSCALE);
        }
    }

    f32x4 oacc[8];
    #pragma unroll
    for (int nt = 0; nt < 8; ++nt) oacc[nt] = (f32x4){0.f, 0.f, 0.f, 0.f};
    float m_[4] = {-1e30f, -1e30f, -1e30f, -1e30f};
    float l_[4] = {0.f, 0.f, 0.f, 0.f};

    float* pf = Pf + w * (16 * PF_STRIDE);

    for (int kb = 0; kb <= qb; ++kb) {
        __syncthreads();   // previous iteration's K/V reads complete

        // ---- stage K block: [64 keys][128 d] fp32 -> bf16 LDS ----
        #pragma unroll
        for (int i = 0; i < 4; ++i) {
            int flat = i * 2048 + tid * 8;
            int key = flat >> 7, d = flat & 127;
            const float* kp = kb_ + ((size_t)((b * T + kb * 64 + key) * KV + g)) * HD + d;
            float4 x0 = *reinterpret_cast<const float4*>(kp);
            float4 x1 = *reinterpret_cast<const float4*>(kp + 4);
            *reinterpret_cast<bf16x8*>(&Ks[key * KS_STRIDE + d]) = pack8(x0, x1, 1.0f);
        }
        // ---- stage V block transposed: [128 hd][64 keys] bf16 ----
        #pragma unroll
        for (int i = 0; i < 4; ++i) {
            int flat = i * 2048 + tid * 8;
            int hd = flat >> 6, key = flat & 63;
            const short* vp = vtb + ((size_t)(b * KV + g) * HD + hd) * T + kb * 64 + key;
            *reinterpret_cast<bf16x8*>(&Vt[hd * VT_STRIDE + key]) =
                *reinterpret_cast<const bf16x8*>(vp);
        }
        __syncthreads();

        // ---- QK^T: 4 key-tiles of 16, K-dim 128 = 4 chunks of 32 ----
        f32x4 sfr[4];
        #pragma unroll
        for (int t = 0; t < 4; ++t) {
            sfr[t] = (f32x4){0.f, 0.f, 0.f, 0.f};
            #pragma unroll
            for (int c = 0; c < 4; ++c) {
                bf16x8 kf = *reinterpret_cast<const bf16x8*>(
                    &Ks[(t * 16 + n16) * KS_STRIDE + c * 32 + quad * 8]);
                sfr[t] = __builtin_amdgcn_mfma_f32_16x16x32_bf16(qf[c], kf, sfr[t], 0, 0, 0);
            }
        }

        // ---- causal mask (diagonal block only) ----
        if (kb == qb) {
            #pragma unroll
            for (int t = 0; t < 4; ++t)
                #pragma unroll
                for (int r = 0; r < 4; ++r)
                    if (t * 16 + n16 > w * 16 + quad * 4 + r) sfr[t][r] = -1e30f;
        }

        // ---- online softmax (rows quad*4+r; stats reduced over 16 lanes) ----
        #pragma unroll
        for (int r = 0; r < 4; ++r) {
            float mloc = fmaxf(fmaxf(sfr[0][r], sfr[1][r]), fmaxf(sfr[2][r], sfr[3][r]));
            #pragma unroll
            for (int msk = 1; msk < 16; msk <<= 1) mloc = fmaxf(mloc, __shfl_xor(mloc, msk));
            float nm = fmaxf(m_[r], mloc);
            float alpha = exp2f(m_[r] - nm);
            m_[r] = nm;
            float ll = 0.f;
            float p0 = exp2f(sfr[0][r] - nm);
            float p1 = exp2f(sfr[1][r] - nm);
            float p2 = exp2f(sfr[2][r] - nm);
            float p3 = exp2f(sfr[3][r] - nm);
            ll = p0 + p1 + p2 + p3;
            #pragma unroll
            for (int msk = 1; msk < 16; msk <<= 1) ll += __shfl_xor(ll, msk);
            l_[r] = l_[r] * alpha + ll;
            // rescale O accumulators (same C-layout row mapping)
            #pragma unroll
            for (int nt = 0; nt < 8; ++nt) oacc[nt][r] *= alpha;
            // write P tile (fp32, per-wave region; no cross-wave sharing)
            pf[(quad * 4 + r) * PF_STRIDE +  0 + n16] = p0;
            pf[(quad * 4 + r) * PF_STRIDE + 16 + n16] = p1;
            pf[(quad * 4 + r) * PF_STRIDE + 32 + n16] = p2;
            pf[(quad * 4 + r) * PF_STRIDE + 48 + n16] = p3;
        }

        // ---- P @ V: 2 key-chunks of 32, 8 hd-tiles of 16 ----
        #pragma unroll
        for (int kc = 0; kc < 2; ++kc) {
            const float* pr = pf + n16 * PF_STRIDE + kc * 32 + quad * 8;
            f32x4 p0 = *reinterpret_cast<const f32x4*>(pr);
            f32x4 p1 = *reinterpret_cast<const f32x4*>(pr + 4);
            bf16x8 af;
            af[0] = f2bf(p0[0]); af[1] = f2bf(p0[1]); af[2] = f2bf(p0[2]); af[3] = f2bf(p0[3]);
            af[4] = f2bf(p1[0]); af[5] = f2bf(p1[1]); af[6] = f2bf(p1[2]); af[7] = f2bf(p1[3]);
            #pragma unroll
            for (int nt = 0; nt < 8; ++nt) {
                bf16x8 vf = *reinterpret_cast<const bf16x8*>(
                    &Vt[(nt * 16 + n16) * VT_STRIDE + kc * 32 + quad * 8]);
                oacc[nt] = __builtin_amdgcn_mfma_f32_16x16x32_bf16(af, vf, oacc[nt], 0, 0, 0);
            }
        }
    }

    // ---- epilogue: O = oacc / l, overwrite q rows ----
    #pragma unroll
    for (int r = 0; r < 4; ++r) {
        float inv = 1.0f / l_[r];
        int row = qb * 64 + w * 16 + quad * 4 + r;
        float* op = qob + ((size_t)(b * T + row) * H + h) * HD;
        #pragma unroll
        for (int nt = 0; nt < 8; ++nt)
            op[nt * 16 + n16] = oacc[nt][r] * inv;
    }
}

// ---------------------------------------------------------------------------
extern "C" void kernel_launch(void* const* d_in, const int* in_sizes, int n_in,
                              void* d_out, int out_size, void* d_ws, size_t ws_size,
                              hipStream_t stream) {
    const float* x  = (const float*)d_in[0];
    const float* wq = (const float*)d_in[1];
    const float* wk = (const float*)d_in[2];
    const float* wv = (const float*)d_in[3];
    const float* wo = (const float*)d_in[4];
    const float* qw = (const float*)d_in[5];
    const float* kw = (const float*)d_in[6];
    const float* fc = (const float*)d_in[7];
    const float* fs = (const float*)d_in[8];
    float* out = (float*)d_out;

    float* qbuf = (float*)d_ws;                          // B*T*H*HD fp32 (Q, then O)
    float* kbuf = qbuf + (size_t)B * T * H * HD;         // B*T*KV*HD fp32
    short* vtb  = (short*)(kbuf + (size_t)B * T * KV * HD); // B*KV*HD*T bf16 (V^T)

    const int M = B * T;   // 4096
    dim3 blk(256);

    // QKV projections (V written transposed bf16 directly)
    gemm_f32<64, 64, 16, 0><<<dim3((H * HD) / 64, M / 64), blk, 0, stream>>>(
        x, wq, (void*)qbuf, M, H * HD, D);
    gemm_f32<64, 64, 16, 0><<<dim3((KV * HD) / 64, M / 64), blk, 0, stream>>>(
        x, wk, (void*)kbuf, M, KV * HD, D);
    gemm_f32<64, 64, 16, 1><<<dim3((KV * HD) / 64, M / 64), blk, 0, stream>>>(
        x, wv, (void*)vtb, M, KV * HD, D);

    // RMSNorm + RoPE on q and k
    {
        int waves = B * T * (H + KV);
        norm_rope<<<dim3((waves * 64) / 256), blk, 0, stream>>>(qbuf, kbuf, qw, kw, fc, fs);
    }

    // MFMA flash attention (O overwrites qbuf)
    attn_mfma<<<dim3(B * H * (T / 64)), blk, 0, stream>>>(qbuf, kbuf, vtb);

    // Output projection
    gemm_f32<64, 64, 16, 0><<<dim3(D / 64, M / 64), blk, 0, stream>>>(
        qbuf, wo, (void*)out, M, D, D);
}

// Round 3
// 533.467 us; speedup vs baseline: 11.2725x; 3.1098x over previous
//
#include <hip/hip_runtime.h>
#include <math.h>

#define B 2
#define T 2048
#define D 2048
#define H 16
#define KV 4
#define HD 128
#define REP (H / KV)

typedef __attribute__((ext_vector_type(8))) short bf16x8;
typedef __attribute__((ext_vector_type(4))) short bf16x4;
typedef __attribute__((ext_vector_type(4))) float f32x4;

// 1/sqrt(128) * log2(e): scores land in log2 domain -> exp2f softmax
#define QSCALE 0.1275177f

__device__ __forceinline__ short f2bf(float f) {
    unsigned int u = __float_as_uint(f);
    unsigned int r = (u + 0x7fffu + ((u >> 16) & 1u)) >> 16;
    return (short)r;
}
__device__ __forceinline__ float bf2f(short s) {
    return __uint_as_float(((unsigned int)(unsigned short)s) << 16);
}
__device__ __forceinline__ bf16x8 pack8(float4 a, float4 b, float s) {
    bf16x8 r;
    r[0] = f2bf(a.x * s); r[1] = f2bf(a.y * s); r[2] = f2bf(a.z * s); r[3] = f2bf(a.w * s);
    r[4] = f2bf(b.x * s); r[5] = f2bf(b.y * s); r[6] = f2bf(b.z * s); r[7] = f2bf(b.w * s);
    return r;
}

#define GLD_LDS16(gp, lp) \
    __builtin_amdgcn_global_load_lds( \
        (const __attribute__((address_space(1))) void*)(gp), \
        (__attribute__((address_space(3))) void*)(lp), 16, 0, 0)

// ---------------------------------------------------------------------------
// fp32 -> bf16 elementwise convert (x)
// ---------------------------------------------------------------------------
__global__ __launch_bounds__(256) void cvt_bf16(
    const float* __restrict__ src, short* __restrict__ dst, int n)
{
    int i = (blockIdx.x * 256 + threadIdx.x) * 8;
    if (i < n) {
        float4 a = *reinterpret_cast<const float4*>(src + i);
        float4 b = *reinterpret_cast<const float4*>(src + i + 4);
        *reinterpret_cast<bf16x8*>(dst + i) = pack8(a, b, 1.0f);
    }
}

// ---------------------------------------------------------------------------
// Transpose + convert: src fp32 [K][N] -> dst bf16 [N][K]
// ---------------------------------------------------------------------------
__global__ __launch_bounds__(256) void transpose_cvt(
    const float* __restrict__ src, short* __restrict__ dst, int K, int N)
{
    __shared__ float tile[32][33];
    const int tx = threadIdx.x & 31, ty = threadIdx.x >> 5;
    const int k0 = blockIdx.y * 32, n0 = blockIdx.x * 32;
    #pragma unroll
    for (int i = 0; i < 4; ++i)
        tile[ty + i * 8][tx] = src[(size_t)(k0 + ty + i * 8) * N + n0 + tx];
    __syncthreads();
    #pragma unroll
    for (int i = 0; i < 4; ++i)
        dst[(size_t)(n0 + ty + i * 8) * K + k0 + tx] = f2bf(tile[tx][ty + i * 8]);
}

// ---------------------------------------------------------------------------
// bf16 MFMA GEMM (m97 structure): C[M,N] = A[M,K] @ Bt[N,K]^T.
// 128x128 tile, BK=32, 256 threads (4 waves, each 64x64 = 4x4 MFMA tiles).
// global_load_lds width-16 staging, 2-barrier K-loop.
// MODE 0: C fp32 row-major.  MODE 1: C bf16 row-major.
// MODE 2: C bf16 transposed for V^T: dst[(b*N + n)*T + (m & 2047)], b = m>>11.
// ---------------------------------------------------------------------------
template<int MODE>
__global__ __launch_bounds__(256) void gemm_bf16(
    const short* __restrict__ A, const short* __restrict__ Bt,
    void* __restrict__ Cv, int M, int N, int K)
{
    __shared__ short As[128 * 32];
    __shared__ short Bs[128 * 32];

    const int tid  = threadIdx.x;
    const int w    = tid >> 6;
    const int lane = tid & 63;
    const int quad = lane >> 4;
    const int n16  = lane & 15;
    const int m0 = blockIdx.y * 128;
    const int n0 = blockIdx.x * 128;
    const int wm = (w >> 1) * 64;
    const int wn = (w & 1) * 64;

    f32x4 acc[4][4];
    #pragma unroll
    for (int i = 0; i < 4; ++i)
        #pragma unroll
        for (int j = 0; j < 4; ++j) acc[i][j] = (f32x4){0.f, 0.f, 0.f, 0.f};

    for (int k0 = 0; k0 < K; k0 += 32) {
        __syncthreads();    // prior iteration's LDS reads complete
        #pragma unroll
        for (int c = 0; c < 2; ++c) {
            int f = c * 2048 + tid * 8;
            int r = f >> 5, cc = f & 31;
            GLD_LDS16(A  + (size_t)(m0 + r) * K + k0 + cc, As + c * 2048 + w * 512);
            GLD_LDS16(Bt + (size_t)(n0 + r) * K + k0 + cc, Bs + c * 2048 + w * 512);
        }
        __syncthreads();    // drains vmcnt: staging complete

        bf16x8 af[4], bf[4];
        #pragma unroll
        for (int i = 0; i < 4; ++i) {
            af[i] = *reinterpret_cast<const bf16x8*>(&As[(wm + i * 16 + n16) * 32 + quad * 8]);
            bf[i] = *reinterpret_cast<const bf16x8*>(&Bs[(wn + i * 16 + n16) * 32 + quad * 8]);
        }
        #pragma unroll
        for (int mi = 0; mi < 4; ++mi)
            #pragma unroll
            for (int ni = 0; ni < 4; ++ni)
                acc[mi][ni] = __builtin_amdgcn_mfma_f32_16x16x32_bf16(
                    af[mi], bf[ni], acc[mi][ni], 0, 0, 0);
    }

    // epilogue: C row = m0+wm+mi*16+quad*4+r, col = n0+wn+ni*16+n16
    if (MODE == 0) {
        float* C = (float*)Cv;
        #pragma unroll
        for (int mi = 0; mi < 4; ++mi)
            #pragma unroll
            for (int ni = 0; ni < 4; ++ni)
                #pragma unroll
                for (int r = 0; r < 4; ++r)
                    C[(size_t)(m0 + wm + mi * 16 + quad * 4 + r) * N
                      + n0 + wn + ni * 16 + n16] = acc[mi][ni][r];
    } else if (MODE == 1) {
        short* C = (short*)Cv;
        #pragma unroll
        for (int mi = 0; mi < 4; ++mi)
            #pragma unroll
            for (int ni = 0; ni < 4; ++ni)
                #pragma unroll
                for (int r = 0; r < 4; ++r)
                    C[(size_t)(m0 + wm + mi * 16 + quad * 4 + r) * N
                      + n0 + wn + ni * 16 + n16] = f2bf(acc[mi][ni][r]);
    } else {
        short* C = (short*)Cv;
        #pragma unroll
        for (int mi = 0; mi < 4; ++mi) {
            int mrow = m0 + wm + mi * 16 + quad * 4;
            int bb = mrow >> 11;
            int t0 = mrow & (T - 1);
            #pragma unroll
            for (int ni = 0; ni < 4; ++ni) {
                int n = n0 + wn + ni * 16 + n16;
                bf16x4 p;
                p[0] = f2bf(acc[mi][ni][0]); p[1] = f2bf(acc[mi][ni][1]);
                p[2] = f2bf(acc[mi][ni][2]); p[3] = f2bf(acc[mi][ni][3]);
                *reinterpret_cast<bf16x4*>(&C[((size_t)bb * N + n) * T + t0]) = p;
            }
        }
    }
}

// ---------------------------------------------------------------------------
// RMSNorm + RoPE on bf16 q and k (in place). One wave per head-row.
// q additionally scaled by QSCALE (folded attention scale + log2e).
// ---------------------------------------------------------------------------
__global__ __launch_bounds__(256) void norm_rope(
    short* __restrict__ q, short* __restrict__ k,
    const float* __restrict__ qw, const float* __restrict__ kw,
    const float* __restrict__ fcos, const float* __restrict__ fsin)
{
    const int wid  = (blockIdx.x * blockDim.x + threadIdx.x) >> 6;
    const int lane = threadIdx.x & 63;
    const int QROWS = B * T * H;

    short* base;
    const float* w;
    int t;
    float scale;
    if (wid < QROWS) {
        t = (wid / H) % T;
        base = q + (size_t)wid * HD;
        w = qw;
        scale = QSCALE;
    } else {
        int rr = wid - QROWS;
        t = (rr / KV) % T;
        base = k + (size_t)rr * HD;
        w = kw;
        scale = 1.0f;
    }

    int pv = *reinterpret_cast<const int*>(&base[2 * lane]);
    float e = bf2f((short)(pv & 0xffff));
    float o = bf2f((short)(pv >> 16));

    float ss = e * e + o * o;
    #pragma unroll
    for (int off = 32; off; off >>= 1) ss += __shfl_xor(ss, off);

    const float rinv = rsqrtf(ss * (1.0f / HD) + 1e-6f);
    e *= rinv * w[2 * lane];
    o *= rinv * w[2 * lane + 1];

    const float c = fcos[t * (HD / 2) + lane];
    const float s = fsin[t * (HD / 2) + lane];
    const float eo = (e * c - o * s) * scale;
    const float oo = (e * s + o * c) * scale;
    int out = ((int)(unsigned short)f2bf(oo) << 16) | (unsigned short)f2bf(eo);
    *reinterpret_cast<int*>(&base[2 * lane]) = out;
}

// ---------------------------------------------------------------------------
// MFMA flash attention (all-bf16 inputs, fp32 accum).
// Grid: B*H*(T/64) workgroups of 256 threads (4 waves).
// O (bf16) overwrites the q rows in-place.
// ---------------------------------------------------------------------------
#define KS_STRIDE 136
#define VT_STRIDE 72
#define PF_STRIDE 68

__global__ __launch_bounds__(256) void attn_mfma(
    short* qob, const short* __restrict__ kb_, const short* __restrict__ vtb)
{
    __shared__ short Ks[64 * KS_STRIDE];
    __shared__ short Vt[128 * VT_STRIDE];
    __shared__ float Pf[4 * 16 * PF_STRIDE];

    const int tid  = threadIdx.x;
    const int w    = tid >> 6;
    const int lane = tid & 63;
    const int quad = lane >> 4;
    const int n16  = lane & 15;

    const int bhq = blockIdx.x;
    const int qb  = 31 - (bhq & 31);      // descending qb: heavy blocks first
    const int h   = (bhq >> 5) & 15;
    const int b   = bhq >> 9;
    const int g   = h >> 2;

    // Q fragments (A-layout), already scaled by QSCALE in norm_rope
    bf16x8 qf[4];
    const int qrow = qb * 64 + w * 16 + n16;
    short* qp = qob + ((size_t)(b * T + qrow) * H + h) * HD;
    #pragma unroll
    for (int c = 0; c < 4; ++c)
        qf[c] = *reinterpret_cast<const bf16x8*>(qp + c * 32 + quad * 8);

    f32x4 oacc[8];
    #pragma unroll
    for (int nt = 0; nt < 8; ++nt) oacc[nt] = (f32x4){0.f, 0.f, 0.f, 0.f};
    float m_[4] = {-1e30f, -1e30f, -1e30f, -1e30f};
    float l_[4] = {0.f, 0.f, 0.f, 0.f};

    float* pf = Pf + w * (16 * PF_STRIDE);

    for (int kb = 0; kb <= qb; ++kb) {
        __syncthreads();

        // stage K block: [64 keys][128 d] bf16
        #pragma unroll
        for (int i = 0; i < 4; ++i) {
            int flat = i * 2048 + tid * 8;
            int key = flat >> 7, d = flat & 127;
            const short* kp = kb_ + ((size_t)((b * T + kb * 64 + key) * KV + g)) * HD + d;
            *reinterpret_cast<bf16x8*>(&Ks[key * KS_STRIDE + d]) =
                *reinterpret_cast<const bf16x8*>(kp);
        }
        // stage V block transposed: [128 hd][64 keys] bf16
        #pragma unroll
        for (int i = 0; i < 4; ++i) {
            int flat = i * 2048 + tid * 8;
            int hd = flat >> 6, key = flat & 63;
            const short* vp = vtb + ((size_t)(b * KV + g) * HD + hd) * T + kb * 64 + key;
            *reinterpret_cast<bf16x8*>(&Vt[hd * VT_STRIDE + key]) =
                *reinterpret_cast<const bf16x8*>(vp);
        }
        __syncthreads();

        // QK^T
        f32x4 sfr[4];
        #pragma unroll
        for (int t = 0; t < 4; ++t) {
            sfr[t] = (f32x4){0.f, 0.f, 0.f, 0.f};
            #pragma unroll
            for (int c = 0; c < 4; ++c) {
                bf16x8 kf = *reinterpret_cast<const bf16x8*>(
                    &Ks[(t * 16 + n16) * KS_STRIDE + c * 32 + quad * 8]);
                sfr[t] = __builtin_amdgcn_mfma_f32_16x16x32_bf16(qf[c], kf, sfr[t], 0, 0, 0);
            }
        }

        if (kb == qb) {   // causal mask, diagonal block only
            #pragma unroll
            for (int t = 0; t < 4; ++t)
                #pragma unroll
                for (int r = 0; r < 4; ++r)
                    if (t * 16 + n16 > w * 16 + quad * 4 + r) sfr[t][r] = -1e30f;
        }

        // online softmax
        #pragma unroll
        for (int r = 0; r < 4; ++r) {
            float mloc = fmaxf(fmaxf(sfr[0][r], sfr[1][r]), fmaxf(sfr[2][r], sfr[3][r]));
            #pragma unroll
            for (int msk = 1; msk < 16; msk <<= 1) mloc = fmaxf(mloc, __shfl_xor(mloc, msk));
            float nm = fmaxf(m_[r], mloc);
            float alpha = exp2f(m_[r] - nm);
            m_[r] = nm;
            float p0 = exp2f(sfr[0][r] - nm);
            float p1 = exp2f(sfr[1][r] - nm);
            float p2 = exp2f(sfr[2][r] - nm);
            float p3 = exp2f(sfr[3][r] - nm);
            float ll = p0 + p1 + p2 + p3;
            #pragma unroll
            for (int msk = 1; msk < 16; msk <<= 1) ll += __shfl_xor(ll, msk);
            l_[r] = l_[r] * alpha + ll;
            #pragma unroll
            for (int nt = 0; nt < 8; ++nt) oacc[nt][r] *= alpha;
            pf[(quad * 4 + r) * PF_STRIDE +  0 + n16] = p0;
            pf[(quad * 4 + r) * PF_STRIDE + 16 + n16] = p1;
            pf[(quad * 4 + r) * PF_STRIDE + 32 + n16] = p2;
            pf[(quad * 4 + r) * PF_STRIDE + 48 + n16] = p3;
        }

        // P @ V
        #pragma unroll
        for (int kc = 0; kc < 2; ++kc) {
            const float* pr = pf + n16 * PF_STRIDE + kc * 32 + quad * 8;
            f32x4 p0 = *reinterpret_cast<const f32x4*>(pr);
            f32x4 p1 = *reinterpret_cast<const f32x4*>(pr + 4);
            bf16x8 af;
            af[0] = f2bf(p0[0]); af[1] = f2bf(p0[1]); af[2] = f2bf(p0[2]); af[3] = f2bf(p0[3]);
            af[4] = f2bf(p1[0]); af[5] = f2bf(p1[1]); af[6] = f2bf(p1[2]); af[7] = f2bf(p1[3]);
            #pragma unroll
            for (int nt = 0; nt < 8; ++nt) {
                bf16x8 vf = *reinterpret_cast<const bf16x8*>(
                    &Vt[(nt * 16 + n16) * VT_STRIDE + kc * 32 + quad * 8]);
                oacc[nt] = __builtin_amdgcn_mfma_f32_16x16x32_bf16(af, vf, oacc[nt], 0, 0, 0);
            }
        }
    }

    // epilogue: O = oacc / l, bf16, in-place over q rows (A operand of O-proj)
    #pragma unroll
    for (int r = 0; r < 4; ++r) {
        float inv = 1.0f / l_[r];
        int row = qb * 64 + w * 16 + quad * 4 + r;
        short* op = qob + ((size_t)(b * T + row) * H + h) * HD;
        #pragma unroll
        for (int nt = 0; nt < 8; ++nt)
            op[nt * 16 + n16] = f2bf(oacc[nt][r] * inv);
    }
}

// ---------------------------------------------------------------------------
extern "C" void kernel_launch(void* const* d_in, const int* in_sizes, int n_in,
                              void* d_out, int out_size, void* d_ws, size_t ws_size,
                              hipStream_t stream) {
    const float* x  = (const float*)d_in[0];
    const float* wq = (const float*)d_in[1];
    const float* wk = (const float*)d_in[2];
    const float* wv = (const float*)d_in[3];
    const float* wo = (const float*)d_in[4];
    const float* qw = (const float*)d_in[5];
    const float* kw = (const float*)d_in[6];
    const float* fc = (const float*)d_in[7];
    const float* fs = (const float*)d_in[8];
    float* out = (float*)d_out;

    // workspace (all bf16/short), woT reuses wqT's slot after Q-GEMM
    short* xb   = (short*)d_ws;                      // B*T*D      = 8388608
    short* wqT  = xb   + (size_t)B * T * D;          // D*D        = 4194304
    short* wkT  = wqT  + (size_t)D * D;              // 512*D      = 1048576
    short* wvT  = wkT  + (size_t)(KV * HD) * D;      // 512*D      = 1048576
    short* qbuf = wvT  + (size_t)(KV * HD) * D;      // B*T*H*HD   = 8388608
    short* kbuf = qbuf + (size_t)B * T * H * HD;     // B*T*KV*HD  = 2097152
    short* vtb  = kbuf + (size_t)B * T * KV * HD;    // B*KV*HD*T  = 2097152
    short* woT  = wqT;                               // alias (wq done by then)

    const int M = B * T;   // 4096
    dim3 blk(256);

    // x -> bf16
    cvt_bf16<<<dim3((B * T * D) / 2048), blk, 0, stream>>>(x, xb, B * T * D);

    // Q projection
    transpose_cvt<<<dim3(D / 32, D / 32), blk, 0, stream>>>(wq, wqT, D, H * HD);
    gemm_bf16<1><<<dim3((H * HD) / 128, M / 128), blk, 0, stream>>>(
        xb, wqT, (void*)qbuf, M, H * HD, D);

    // K projection
    transpose_cvt<<<dim3((KV * HD) / 32, D / 32), blk, 0, stream>>>(wk, wkT, D, KV * HD);
    gemm_bf16<1><<<dim3((KV * HD) / 128, M / 128), blk, 0, stream>>>(
        xb, wkT, (void*)kbuf, M, KV * HD, D);

    // V projection (written directly as V^T bf16)
    transpose_cvt<<<dim3((KV * HD) / 32, D / 32), blk, 0, stream>>>(wv, wvT, D, KV * HD);
    gemm_bf16<2><<<dim3((KV * HD) / 128, M / 128), blk, 0, stream>>>(
        xb, wvT, (void*)vtb, M, KV * HD, D);

    // RMSNorm + RoPE (q also picks up QSCALE)
    {
        int waves = B * T * (H + KV);
        norm_rope<<<dim3((waves * 64) / 256), blk, 0, stream>>>(qbuf, kbuf, qw, kw, fc, fs);
    }

    // flash attention, O overwrites qbuf (bf16)
    attn_mfma<<<dim3(B * H * (T / 64)), blk, 0, stream>>>(qbuf, kbuf, vtb);

    // O projection -> fp32 out
    transpose_cvt<<<dim3(D / 32, D / 32), blk, 0, stream>>>(wo, woT, H * HD, D);
    gemm_bf16<0><<<dim3(D / 128, M / 128), blk, 0, stream>>>(
        qbuf, woT, (void*)out, M, D, H * HD);
}